// Round 1
// baseline (98.672 us; speedup 1.0000x reference)
//
#include <hip/hip_runtime.h>

// out[b] = cos(weights[0]) * cos(x[b,0])
//
// Derivation: the 2-qubit circuit RY(x)⊗RX(w) + CNOT(0->1) measured on Z_0
// collapses algebraically:
//   <Z_0> = (|b0_q0|^2 - |b1_q0|^2) * (|b0_q1|^2 + |b1_q1|^2)
// The qubit-1 factor is 1 (unitarity), and the qubit-0 factor is
//   (cos^2(w0/2)-sin^2(w0/2)) * (cos^2(x0/2)-sin^2(x0/2)) = cos(w0)*cos(x0).
// CNOT only permutes within the q0=1 row, leaving P(q0) unchanged.
//
// => pure streaming kernel: read x (interleaved [B,2] f32, use col 0),
//    write [B] f32. Memory-bound: ~96 MiB total traffic.

__global__ void __launch_bounds__(256)
qlayer_kernel(const float4* __restrict__ x4,   // x viewed as float4: 2 batch rows each
              const float* __restrict__ w,     // weights[2]
              float2* __restrict__ out2,       // out viewed as float2
              int n4)                          // number of float4s = B/2
{
    const float cw = cosf(w[0]);   // uniform; scalar-cached load + one cos
    const int stride = gridDim.x * blockDim.x;
    for (int i = blockIdx.x * blockDim.x + threadIdx.x; i < n4; i += stride) {
        const float4 v = x4[i];    // v.x = x[2i,0], v.y = x[2i,1], v.z = x[2i+1,0], v.w = x[2i+1,1]
        float2 o;
        o.x = cw * cosf(v.x);
        o.y = cw * cosf(v.z);
        out2[i] = o;
    }
}

extern "C" void kernel_launch(void* const* d_in, const int* in_sizes, int n_in,
                              void* d_out, int out_size, void* d_ws, size_t ws_size,
                              hipStream_t stream) {
    const float4* x4 = (const float4*)d_in[0];      // [B,2] f32 -> B/2 float4
    const float*  w  = (const float*)d_in[1];       // [2] f32
    float2* out2 = (float2*)d_out;                  // [B] f32 -> B/2 float2

    const int n4 = in_sizes[0] / 4;                 // B*2 floats / 4 = B/2 float4s
    const int block = 256;
    // Memory-bound: cap grid at ~2048 blocks and grid-stride (G11).
    int blocks = (n4 + block - 1) / block;
    if (blocks > 2048) blocks = 2048;

    qlayer_kernel<<<blocks, block, 0, stream>>>(x4, w, out2, n4);
}